// Round 2
// baseline (419.751 us; speedup 1.0000x reference)
//
#include <hip/hip_runtime.h>
#include <math.h>

// Problem constants (B=2,S=2048 -> T=4096; D=H=1024; E=16; K=2; CF=1.25)
#define T_TOK 4096
#define DIM   1024
#define HID   1024
#define NE    16
#define CAP   640      // ceil(T*K/E*CF)
#define CBUF  1280     // K*CAP
#define BM 128
#define BN 64
#define BK 32
#define MAXTILE 160

typedef __attribute__((ext_vector_type(8))) short short8;   // 8 bf16 (4 VGPRs)
typedef __attribute__((ext_vector_type(4))) float f32x4;    // MFMA accumulator

static __device__ __forceinline__ unsigned short f2bf(float f) {
    unsigned int u = __float_as_uint(f);
    u += 0x7fff + ((u >> 16) & 1);   // RNE
    return (unsigned short)(u >> 16);
}

// component pick that stays compile-time under #pragma unroll (rule #20)
#define PICK4(v,i) ((i)==0?(v).x:(i)==1?(v).y:(i)==2?(v).z:(v).w)

// async global->LDS DMA, 16B/lane; dst wave-uniform base, lane i -> dst+16*i.
// A-rows are 64B = 4 chunks; chunk c of row r stored at c^((r>>1)&3) (source-side
// permute) so ds_read_b128 fragment reads are 2-way (free) without padding.
static __device__ __forceinline__ void async16(const void* g, void* l) {
    __builtin_amdgcn_global_load_lds((const __attribute__((address_space(1))) void*)g,
                                     (__attribute__((address_space(3))) void*)l, 16, 0, 0);
}

// ---------------- x -> bf16 (with zero padding row at index T) ----------------
__global__ void convert_x_k(const float* __restrict__ x, unsigned short* __restrict__ xb) {
    int i = blockIdx.x * blockDim.x + threadIdx.x;
    int base = i * 4;
    int row = base >> 10;
    ushort4 o;
    if (row < T_TOK) {
        float4 v = *(const float4*)(x + base);
        o.x = f2bf(v.x); o.y = f2bf(v.y); o.z = f2bf(v.z); o.w = f2bf(v.w);
    } else {
        o.x = 0; o.y = 0; o.z = 0; o.w = 0;
    }
    *(ushort4*)(xb + base) = o;
}

// ---------------- router: logits, softmax, top-2 (one wave per token) ----------------
__global__ void router_k(const float* __restrict__ x, const float* __restrict__ rw,
                         int* __restrict__ route_e, float* __restrict__ route_w) {
    int t = blockIdx.x;
    int lane = threadIdx.x;
    const float* xr = x + (size_t)t * DIM + lane * 16;
    float4 xv0 = *(const float4*)(xr + 0);
    float4 xv1 = *(const float4*)(xr + 4);
    float4 xv2 = *(const float4*)(xr + 8);
    float4 xv3 = *(const float4*)(xr + 12);
    float xl[16] = {xv0.x, xv0.y, xv0.z, xv0.w, xv1.x, xv1.y, xv1.z, xv1.w,
                    xv2.x, xv2.y, xv2.z, xv2.w, xv3.x, xv3.y, xv3.z, xv3.w};
    float p[16];
    #pragma unroll
    for (int e = 0; e < 16; ++e) p[e] = 0.f;
    #pragma unroll
    for (int j = 0; j < 16; ++j) {
        const float4* rp = (const float4*)(rw + (size_t)(lane * 16 + j) * 16);
        float4 r0 = rp[0], r1 = rp[1], r2 = rp[2], r3 = rp[3];
        float xv = xl[j];
        p[0]  += xv * r0.x; p[1]  += xv * r0.y; p[2]  += xv * r0.z; p[3]  += xv * r0.w;
        p[4]  += xv * r1.x; p[5]  += xv * r1.y; p[6]  += xv * r1.z; p[7]  += xv * r1.w;
        p[8]  += xv * r2.x; p[9]  += xv * r2.y; p[10] += xv * r2.z; p[11] += xv * r2.w;
        p[12] += xv * r3.x; p[13] += xv * r3.y; p[14] += xv * r3.z; p[15] += xv * r3.w;
    }
    #pragma unroll
    for (int off = 32; off > 0; off >>= 1) {
        #pragma unroll
        for (int e = 0; e < 16; ++e) p[e] += __shfl_xor(p[e], off);
    }
    if (lane == 0) {
        float m = p[0];
        #pragma unroll
        for (int e = 1; e < 16; ++e) m = fmaxf(m, p[e]);
        float s = 0.f;
        #pragma unroll
        for (int e = 0; e < 16; ++e) s = s + __expf(p[e] - m);
        float v0 = -1e30f, v1 = -1e30f; int i0 = 0, i1 = 0;
        #pragma unroll
        for (int e = 0; e < 16; ++e) {
            float v = p[e];
            if (v > v0)      { v1 = v0; i1 = i0; v0 = v; i0 = e; }
            else if (v > v1) { v1 = v;  i1 = e; }
        }
        route_e[t*2+0] = i0;  route_e[t*2+1] = i1;
        route_w[t*2+0] = __expf(v0 - m) / s;
        route_w[t*2+1] = __expf(v1 - m) / s;
    }
}

// ------- dispatch build: ballot rank/slot + inverse map smap + tile list -------
__global__ __launch_bounds__(1024)
void build_dispatch_k(const int* __restrict__ route_e, const float* __restrict__ route_w,
                      int* __restrict__ disp, int* __restrict__ smap, int* __restrict__ tmeta) {
    __shared__ unsigned char eidx[2 * T_TOK];
    __shared__ unsigned char keepf[2 * T_TOK];
    __shared__ int totals[NE];
    int tid = threadIdx.x;
    int wv = tid >> 6, lane = tid & 63;

    {   // route_e (8192 ints) -> bytes, coalesced
        int4 a = ((const int4*)route_e)[tid * 2];
        int4 b = ((const int4*)route_e)[tid * 2 + 1];
        unsigned int lo = (a.x & 0xff) | ((a.y & 0xff) << 8) | ((a.z & 0xff) << 16) | ((a.w & 0xff) << 24);
        unsigned int hi = (b.x & 0xff) | ((b.y & 0xff) << 8) | ((b.z & 0xff) << 16) | ((b.w & 0xff) << 24);
        uint2 pk; pk.x = lo; pk.y = hi;
        *(uint2*)(eidx + tid * 8) = pk;
    }
    for (int i = tid; i < 2 * T_TOK; i += 1024) smap[i] = -1;
    __syncthreads();

    unsigned long long below = (lane == 0) ? 0ull : ((~0ull) >> (64 - lane));
    #pragma unroll
    for (int s = 0; s < 2; ++s) {      // keep = token-order rank in (e,k) stream < CAP
        int st = wv + s * 16;
        int e = st >> 1, k = st & 1;
        int run = 0;
        for (int base = 0; base < T_TOK; base += 64) {
            int t = base + lane;
            int hit = (eidx[t * 2 + k] == e);
            unsigned long long m = __ballot(hit);
            int rank = run + __popcll(m & below);
            if (hit) keepf[t * 2 + k] = (rank < CAP) ? 1 : 0;
            run += __popcll(m);
        }
    }
    __syncthreads();

    {   // slot = flat-order rank among kept entries of expert e (one wave per expert)
        int e = wv;
        int run = 0;
        for (int base = 0; base < 2 * T_TOK; base += 64) {
            int f = base + lane;
            int hit = (eidx[f] == e) && keepf[f];
            unsigned long long m = __ballot(hit);
            int slot = run + __popcll(m & below);
            if (hit) {
                disp[e * CBUF + slot] = f >> 1;
                smap[f] = e * CBUF + slot;
            }
            run += __popcll(m);
        }
        if (lane == 0) totals[e] = run;
    }
    __syncthreads();

    for (int i = tid; i < NE * CBUF; i += 1024) {   // pad unused slots -> zero row
        int e = i / CBUF, s = i - e * CBUF;
        if (s >= totals[e]) disp[i] = T_TOK;
    }

    if (tid == 0) {   // active-tile list
        int n = 0;
        for (int e = 0; e < NE; ++e) {
            int ntl = (totals[e] + BM - 1) / BM;
            for (int m = 0; m < ntl; ++m) { tmeta[4 + n] = (e << 8) | m; ++n; }
        }
        tmeta[0] = n;
    }
}

// ---------------- GEMM1: xe @ {gate,up} fused + SiLU -> hidden (bf16) ----------------
// R7: B staged inline from fp32 [e][d][h] (d=k, h=n): per K-step each thread
// loads a 4k x 4n fp32 patch coalesced (256B bursts/row-instr), converts to
// bf16, and writes k-packed ds_write_b64 into Bs[n][k].  LDS chunk swizzle
// s(n)=(n>>2)&3 (chunk c of row n holds source chunk c^s(n)); read side uses
// swqB = quad ^ ((ln>>2)&3).  A-tile keeps the global_load_lds DMA path with
// its original s(r)=(r>>1)&3 swizzle (swqA).  This removes the standalone
// transpose_cvt_k kernel (measured structurally capped at ~2.2 TB/s / 90 us).
__global__ __launch_bounds__(256, 2)
void gemm1_k(const unsigned short* __restrict__ xb, const float* __restrict__ gw,
             const float* __restrict__ uw, const int* __restrict__ disp,
             const int* __restrict__ tmeta, unsigned short* __restrict__ hidden) {
    int slot = blockIdx.y;
    if (slot >= tmeta[0]) return;
    int pk = tmeta[4 + slot];
    int e = pk >> 8, mt = pk & 255;
    int m0 = mt * BM, n0 = blockIdx.x * BN;

    __shared__ unsigned short As[2 * BM * BK];   // 16 KB
    __shared__ unsigned short Bg[2 * BN * BK];   // 8 KB
    __shared__ unsigned short Bu[2 * BN * BK];   // 8 KB
    __shared__ int tok[BM];
    int tid = threadIdx.x;
    if (tid < BM) tok[tid] = disp[e * CBUF + m0 + tid];
    __syncthreads();

    int lane = tid & 63, w = tid >> 6;
    // ---- A staging (DMA, unchanged) ----
    int cg = (lane & 3) ^ ((lane >> 3) & 3);   // swizzled source chunk
    int rl = lane >> 2;                         // local row in 16-row group
    int rA0 = w * 32 + rl, rA1 = rA0 + 16;
    const unsigned short* srcA0 = xb + (size_t)tok[rA0] * DIM + cg * 8;
    const unsigned short* srcA1 = xb + (size_t)tok[rA1] * DIM + cg * 8;
    unsigned short* dA0 = As + (w * 32) * BK;
    unsigned short* dA1 = As + (w * 32 + 16) * BK;

    // ---- B staging (reg path): mat = waves 0-1 gate, 2-3 up ----
    int matb = tid >> 7;                 // 0 = gate, 1 = up
    int kidx = (tid >> 4) & 7;           // 0..7 -> k4 = 0..28
    int k4 = kidx * 4;
    int g = tid & 15;                    // n-group: n = g*4 + i
    const float* Wsrc = (matb ? uw : gw) + (size_t)e * DIM * HID + (size_t)k4 * HID + n0 + g * 4;
    unsigned short* Bmine = matb ? Bu : Bg;
    // s(n) = (n>>2)&3 = g&3 for all 4 i; chunk + half offset uniform per thread
    int bOff = (((k4 >> 3) ^ (g & 3)) << 3) + ((k4 >> 2) & 1) * 4;   // u16 units

    int wm = w >> 1, wn = w & 1;
    int quad = lane >> 4, ln = lane & 15;
    int swqA = quad ^ ((ln >> 1) & 3);
    int swqB = quad ^ ((ln >> 2) & 3);

    f32x4 zero4 = {0.f, 0.f, 0.f, 0.f};
    f32x4 accg[4][2], accu[4][2];
    #pragma unroll
    for (int i = 0; i < 4; ++i)
        #pragma unroll
        for (int j = 0; j < 2; ++j) { accg[i][j] = zero4; accu[i][j] = zero4; }

    // ---- prologue: stage tile 0 into buffer 0 ----
    {
        float4 r0 = *(const float4*)(Wsrc);
        float4 r1 = *(const float4*)(Wsrc + 1024);
        float4 r2 = *(const float4*)(Wsrc + 2048);
        float4 r3 = *(const float4*)(Wsrc + 3072);
        async16(srcA0, dA0); async16(srcA1, dA1);
        #pragma unroll
        for (int i = 0; i < 4; ++i) {
            uint2 pkv;
            pkv.x = (unsigned int)f2bf(PICK4(r0, i)) | ((unsigned int)f2bf(PICK4(r1, i)) << 16);
            pkv.y = (unsigned int)f2bf(PICK4(r2, i)) | ((unsigned int)f2bf(PICK4(r3, i)) << 16);
            *(uint2*)(Bmine + (g * 4 + i) * BK + bOff) = pkv;
        }
        asm volatile("s_waitcnt vmcnt(0) lgkmcnt(0)\n\ts_barrier" ::: "memory");
    }

    for (int k0 = 0; k0 < DIM; k0 += BK) {
        int cur = (k0 >> 5) & 1, nx = cur ^ 1;
        float4 r0, r1, r2, r3;
        if (k0 + BK < DIM) {
            const float* Ws = Wsrc + (size_t)(k0 + BK) * 1024;
            r0 = *(const float4*)(Ws);
            r1 = *(const float4*)(Ws + 1024);
            r2 = *(const float4*)(Ws + 2048);
            r3 = *(const float4*)(Ws + 3072);
            async16(srcA0 + k0 + BK, dA0 + nx * (BM * BK));
            async16(srcA1 + k0 + BK, dA1 + nx * (BM * BK));
        }
        const unsigned short* Ab = As + cur * (BM * BK);
        const unsigned short* Gb = Bg + cur * (BN * BK);
        const unsigned short* Ub = Bu + cur * (BN * BK);
        short8 af[4], bgf[2], buf2[2];
        #pragma unroll
        for (int i = 0; i < 4; ++i)
            af[i] = *(const short8*)(Ab + (wm * 64 + i * 16 + ln) * BK + swqA * 8);
        #pragma unroll
        for (int j = 0; j < 2; ++j) {
            bgf[j]  = *(const short8*)(Gb + (wn * 32 + j * 16 + ln) * BK + swqB * 8);
            buf2[j] = *(const short8*)(Ub + (wn * 32 + j * 16 + ln) * BK + swqB * 8);
        }
        #pragma unroll
        for (int i = 0; i < 4; ++i)
            #pragma unroll
            for (int j = 0; j < 2; ++j) {
                accg[i][j] = __builtin_amdgcn_mfma_f32_16x16x32_bf16(af[i], bgf[j],  accg[i][j], 0, 0, 0);
                accu[i][j] = __builtin_amdgcn_mfma_f32_16x16x32_bf16(af[i], buf2[j], accu[i][j], 0, 0, 0);
            }
        if (k0 + BK < DIM) {
            #pragma unroll
            for (int i = 0; i < 4; ++i) {
                uint2 pkv;
                pkv.x = (unsigned int)f2bf(PICK4(r0, i)) | ((unsigned int)f2bf(PICK4(r1, i)) << 16);
                pkv.y = (unsigned int)f2bf(PICK4(r2, i)) | ((unsigned int)f2bf(PICK4(r3, i)) << 16);
                *(uint2*)(Bmine + nx * (BN * BK) + (g * 4 + i) * BK + bOff) = pkv;
            }
        }
        // drain: own A-DMA landed in nx, own B ds_writes visible; barrier syncs waves
        asm volatile("s_waitcnt vmcnt(0) lgkmcnt(0)\n\ts_barrier" ::: "memory");
    }
    #pragma unroll
    for (int i = 0; i < 4; ++i) {
        #pragma unroll
        for (int r = 0; r < 4; ++r) {
            int row = m0 + wm * 64 + i * 16 + quad * 4 + r;
            unsigned short* hrow = hidden + ((size_t)e * CBUF + row) * HID + n0 + wn * 32 + ln;
            #pragma unroll
            for (int j = 0; j < 2; ++j) {
                float gv = accg[i][j][r];
                float uv = accu[i][j][r];
                float sg = gv / (1.f + __expf(-gv));
                hrow[j * 16] = f2bf(sg * uv);
            }
        }
    }
}

// ---------------- GEMM2: hidden @ down -> ebuf (bf16, per expert slot) ----------------
// Same inline B-staging from fp32 down_w [e][h][d] (h=k, d=n).
__global__ __launch_bounds__(256, 2)
void gemm2_k(const unsigned short* __restrict__ hidden, const float* __restrict__ dw,
             const int* __restrict__ tmeta, unsigned short* __restrict__ ebuf) {
    int slot = blockIdx.y;
    if (slot >= tmeta[0]) return;
    int pk = tmeta[4 + slot];
    int e = pk >> 8, mt = pk & 255;
    int m0 = mt * BM, n0 = blockIdx.x * BN;

    __shared__ unsigned short As[2 * BM * BK];   // 16 KB
    __shared__ unsigned short Bs[2 * BN * BK];   // 8 KB
    int tid = threadIdx.x;

    int lane = tid & 63, w = tid >> 6;
    int cg = (lane & 3) ^ ((lane >> 3) & 3);
    int rl = lane >> 2;
    int rA0 = w * 32 + rl, rA1 = rA0 + 16;
    const unsigned short* srcA0 = hidden + ((size_t)e * CBUF + m0 + rA0) * HID + cg * 8;
    const unsigned short* srcA1 = hidden + ((size_t)e * CBUF + m0 + rA1) * HID + cg * 8;
    unsigned short* dA0 = As + (w * 32) * BK;
    unsigned short* dA1 = As + (w * 32 + 16) * BK;

    // B staging: thread -> 4k x 2n fp32 patch; n = g2*2 + i, k4 = kidx2*4
    int g2 = tid & 31;
    int kidx2 = ((tid >> 5) & 3) | ((tid >> 7) << 2);
    int k4 = kidx2 * 4;
    const float* Wsrc = dw + (size_t)e * HID * DIM + (size_t)k4 * DIM + n0 + g2 * 2;
    // s(n) = (n>>2)&3 = (g2>>1)&3 for both i
    int bOff = (((k4 >> 3) ^ ((g2 >> 1) & 3)) << 3) + ((k4 >> 2) & 1) * 4;

    int wm = w >> 1, wn = w & 1;
    int quad = lane >> 4, ln = lane & 15;
    int swqA = quad ^ ((ln >> 1) & 3);
    int swqB = quad ^ ((ln >> 2) & 3);

    f32x4 zero4 = {0.f, 0.f, 0.f, 0.f};
    f32x4 acc[4][2];
    #pragma unroll
    for (int i = 0; i < 4; ++i)
        #pragma unroll
        for (int j = 0; j < 2; ++j) acc[i][j] = zero4;

    {   // prologue: tile 0 -> buffer 0
        float2 r0 = *(const float2*)(Wsrc);
        float2 r1 = *(const float2*)(Wsrc + 1024);
        float2 r2 = *(const float2*)(Wsrc + 2048);
        float2 r3 = *(const float2*)(Wsrc + 3072);
        async16(srcA0, dA0); async16(srcA1, dA1);
        #pragma unroll
        for (int i = 0; i < 2; ++i) {
            uint2 pkv;
            pkv.x = (unsigned int)f2bf(i ? r0.y : r0.x) | ((unsigned int)f2bf(i ? r1.y : r1.x) << 16);
            pkv.y = (unsigned int)f2bf(i ? r2.y : r2.x) | ((unsigned int)f2bf(i ? r3.y : r3.x) << 16);
            *(uint2*)(Bs + (g2 * 2 + i) * BK + bOff) = pkv;
        }
        asm volatile("s_waitcnt vmcnt(0) lgkmcnt(0)\n\ts_barrier" ::: "memory");
    }

    for (int k0 = 0; k0 < HID; k0 += BK) {
        int cur = (k0 >> 5) & 1, nx = cur ^ 1;
        float2 r0, r1, r2, r3;
        if (k0 + BK < HID) {
            const float* Ws = Wsrc + (size_t)(k0 + BK) * 1024;
            r0 = *(const float2*)(Ws);
            r1 = *(const float2*)(Ws + 1024);
            r2 = *(const float2*)(Ws + 2048);
            r3 = *(const float2*)(Ws + 3072);
            async16(srcA0 + k0 + BK, dA0 + nx * (BM * BK));
            async16(srcA1 + k0 + BK, dA1 + nx * (BM * BK));
        }
        const unsigned short* Ab = As + cur * (BM * BK);
        const unsigned short* Bb = Bs + cur * (BN * BK);
        short8 af[4], bf[2];
        #pragma unroll
        for (int i = 0; i < 4; ++i)
            af[i] = *(const short8*)(Ab + (wm * 64 + i * 16 + ln) * BK + swqA * 8);
        #pragma unroll
        for (int j = 0; j < 2; ++j)
            bf[j] = *(const short8*)(Bb + (wn * 32 + j * 16 + ln) * BK + swqB * 8);
        #pragma unroll
        for (int i = 0; i < 4; ++i)
            #pragma unroll
            for (int j = 0; j < 2; ++j)
                acc[i][j] = __builtin_amdgcn_mfma_f32_16x16x32_bf16(af[i], bf[j], acc[i][j], 0, 0, 0);
        if (k0 + BK < HID) {
            #pragma unroll
            for (int i = 0; i < 2; ++i) {
                uint2 pkv;
                pkv.x = (unsigned int)f2bf(i ? r0.y : r0.x) | ((unsigned int)f2bf(i ? r1.y : r1.x) << 16);
                pkv.y = (unsigned int)f2bf(i ? r2.y : r2.x) | ((unsigned int)f2bf(i ? r3.y : r3.x) << 16);
                *(uint2*)(Bs + nx * (BN * BK) + (g2 * 2 + i) * BK + bOff) = pkv;
            }
        }
        asm volatile("s_waitcnt vmcnt(0) lgkmcnt(0)\n\ts_barrier" ::: "memory");
    }
    #pragma unroll
    for (int i = 0; i < 4; ++i) {
        #pragma unroll
        for (int r = 0; r < 4; ++r) {
            int row = m0 + wm * 64 + i * 16 + quad * 4 + r;
            unsigned short* erow = ebuf + ((size_t)e * CBUF + row) * DIM + n0 + wn * 32 + ln;
            #pragma unroll
            for (int j = 0; j < 2; ++j)
                erow[j * 16] = f2bf(acc[i][j][r]);
        }
    }
}

// ---------------- combine: out[t] = sum_k w[t,k] * ebuf[smap[t,k]] ----------------
__global__ __launch_bounds__(256)
void combine_k(const unsigned short* __restrict__ ebuf, const int* __restrict__ smap,
               const float* __restrict__ rwt, float* __restrict__ out) {
    int t = blockIdx.x * 2 + (threadIdx.x >> 7);
    int c = (threadIdx.x & 127) * 8;
    float acc[8];
    #pragma unroll
    for (int j = 0; j < 8; ++j) acc[j] = 0.f;
    #pragma unroll
    for (int k = 0; k < 2; ++k) {
        int sm = smap[t * 2 + k];
        if (sm >= 0) {
            float wgt = rwt[t * 2 + k];
            uint4 rv = *(const uint4*)(ebuf + (size_t)sm * DIM + c);
            unsigned int d[4] = {rv.x, rv.y, rv.z, rv.w};
            #pragma unroll
            for (int q = 0; q < 4; ++q) {
                acc[q * 2 + 0] += wgt * __uint_as_float(d[q] << 16);
                acc[q * 2 + 1] += wgt * __uint_as_float(d[q] & 0xffff0000u);
            }
        }
    }
    float4 o0 = {acc[0], acc[1], acc[2], acc[3]};
    float4 o1 = {acc[4], acc[5], acc[6], acc[7]};
    float* orow = out + (size_t)t * DIM + c;
    *(float4*)(orow + 0) = o0;
    *(float4*)(orow + 4) = o1;
}

extern "C" void kernel_launch(void* const* d_in, const int* in_sizes, int n_in,
                              void* d_out, int out_size, void* d_ws, size_t ws_size,
                              hipStream_t stream) {
    const float* x  = (const float*)d_in[0];   // (2,2048,1024)
    const float* rw = (const float*)d_in[1];   // (1024,16)
    const float* gw = (const float*)d_in[2];   // (16,1024,1024) [e][d][h]
    const float* uw = (const float*)d_in[3];   // (16,1024,1024) [e][d][h]
    const float* dw = (const float*)d_in[4];   // (16,1024,1024) [e][h][d]
    float* out = (float*)d_out;

    char* ws = (char*)d_ws;
    size_t off = 0;
    auto alloc = [&](size_t bytes) { void* p = ws + off; off += (bytes + 255) & ~(size_t)255; return p; };
    unsigned short* xb   = (unsigned short*)alloc((size_t)(T_TOK + 1) * DIM * 2);
    unsigned short* hid  = (unsigned short*)alloc((size_t)NE * CBUF * HID * 2);
    unsigned short* ebuf = (unsigned short*)alloc((size_t)NE * CBUF * DIM * 2);
    int*   disp   = (int*)alloc((size_t)NE * CBUF * 4);
    int*   smap   = (int*)alloc((size_t)T_TOK * 2 * 4);
    int*   tmeta  = (int*)alloc((4 + MAXTILE) * 4);
    int*   re     = (int*)alloc((size_t)T_TOK * 2 * 4);
    float* rwt    = (float*)alloc((size_t)T_TOK * 2 * 4);
    (void)ws_size; (void)in_sizes; (void)n_in;

    convert_x_k<<<T_TOK + 1, 256, 0, stream>>>(x, xb);
    router_k<<<T_TOK, 64, 0, stream>>>(x, rw, re, rwt);
    build_dispatch_k<<<1, 1024, 0, stream>>>(re, rwt, disp, smap, tmeta);
    gemm1_k<<<dim3(HID / BN, MAXTILE), 256, 0, stream>>>(xb, gw, uw, disp, tmeta, hid);
    gemm2_k<<<dim3(DIM / BN, MAXTILE), 256, 0, stream>>>(hid, dw, tmeta, ebuf);
    combine_k<<<T_TOK / 2, 256, 0, stream>>>(ebuf, smap, rwt, out);
}

// Round 3
// 400.213 us; speedup vs baseline: 1.0488x; 1.0488x over previous
//
#include <hip/hip_runtime.h>
#include <hip/hip_bf16.h>
#include <math.h>

// Problem constants (B=2,S=2048 -> T=4096; D=H=1024; E=16; K=2; CF=1.25)
#define T_TOK 4096
#define DIM   1024
#define HID   1024
#define NE    16
#define CAP   640      // ceil(T*K/E*CF)
#define CBUF  1280     // K*CAP
#define BM 128
#define BN 64
#define BK 32
#define MAXTILE 160

typedef __attribute__((ext_vector_type(8))) short short8;   // 8 bf16 (4 VGPRs)
typedef __attribute__((ext_vector_type(4))) float f32x4;    // MFMA accumulator

static __device__ __forceinline__ unsigned short f2bf(float f) {
    unsigned int u = __float_as_uint(f);
    u += 0x7fff + ((u >> 16) & 1);   // RNE
    return (unsigned short)(u >> 16);
}

// RNE pair-convert; compiler emits v_cvt_pk_bf16_f32 (bit-identical to f2bf pairs)
static __device__ __forceinline__ unsigned int pack2bf(float lo, float hi) {
    union { __hip_bfloat162 h; unsigned int u; } cv;
    cv.h = __float22bfloat162_rn(make_float2(lo, hi));
    return cv.u;
}

// component pick that stays compile-time under #pragma unroll (rule #20)
#define PICK4(v,i) ((i)==0?(v).x:(i)==1?(v).y:(i)==2?(v).z:(v).w)

// async global->LDS DMA, 16B/lane; dst wave-uniform base, lane i -> dst+16*i.
// A-rows are 64B = 4 chunks; chunk c of row r stored at c^((r>>1)&3) (source-side
// permute) so ds_read_b128 fragment reads are 2-way (free) without padding.
static __device__ __forceinline__ void async16(const void* g, void* l) {
    __builtin_amdgcn_global_load_lds((const __attribute__((address_space(1))) void*)g,
                                     (__attribute__((address_space(3))) void*)l, 16, 0, 0);
}

// ---------------- x -> bf16 (with zero padding row at index T) ----------------
__global__ void convert_x_k(const float* __restrict__ x, unsigned short* __restrict__ xb) {
    int i = blockIdx.x * blockDim.x + threadIdx.x;
    int base = i * 4;
    int row = base >> 10;
    ushort4 o;
    if (row < T_TOK) {
        float4 v = *(const float4*)(x + base);
        o.x = f2bf(v.x); o.y = f2bf(v.y); o.z = f2bf(v.z); o.w = f2bf(v.w);
    } else {
        o.x = 0; o.y = 0; o.z = 0; o.w = 0;
    }
    *(ushort4*)(xb + base) = o;
}

// ---------------- router: logits, softmax, top-2 (one wave per token) ----------------
__global__ void router_k(const float* __restrict__ x, const float* __restrict__ rw,
                         int* __restrict__ route_e, float* __restrict__ route_w) {
    int t = blockIdx.x;
    int lane = threadIdx.x;
    const float* xr = x + (size_t)t * DIM + lane * 16;
    float4 xv0 = *(const float4*)(xr + 0);
    float4 xv1 = *(const float4*)(xr + 4);
    float4 xv2 = *(const float4*)(xr + 8);
    float4 xv3 = *(const float4*)(xr + 12);
    float xl[16] = {xv0.x, xv0.y, xv0.z, xv0.w, xv1.x, xv1.y, xv1.z, xv1.w,
                    xv2.x, xv2.y, xv2.z, xv2.w, xv3.x, xv3.y, xv3.z, xv3.w};
    float p[16];
    #pragma unroll
    for (int e = 0; e < 16; ++e) p[e] = 0.f;
    #pragma unroll
    for (int j = 0; j < 16; ++j) {
        const float4* rp = (const float4*)(rw + (size_t)(lane * 16 + j) * 16);
        float4 r0 = rp[0], r1 = rp[1], r2 = rp[2], r3 = rp[3];
        float xv = xl[j];
        p[0]  += xv * r0.x; p[1]  += xv * r0.y; p[2]  += xv * r0.z; p[3]  += xv * r0.w;
        p[4]  += xv * r1.x; p[5]  += xv * r1.y; p[6]  += xv * r1.z; p[7]  += xv * r1.w;
        p[8]  += xv * r2.x; p[9]  += xv * r2.y; p[10] += xv * r2.z; p[11] += xv * r2.w;
        p[12] += xv * r3.x; p[13] += xv * r3.y; p[14] += xv * r3.z; p[15] += xv * r3.w;
    }
    #pragma unroll
    for (int off = 32; off > 0; off >>= 1) {
        #pragma unroll
        for (int e = 0; e < 16; ++e) p[e] += __shfl_xor(p[e], off);
    }
    if (lane == 0) {
        float m = p[0];
        #pragma unroll
        for (int e = 1; e < 16; ++e) m = fmaxf(m, p[e]);
        float s = 0.f;
        #pragma unroll
        for (int e = 0; e < 16; ++e) s = s + __expf(p[e] - m);
        float v0 = -1e30f, v1 = -1e30f; int i0 = 0, i1 = 0;
        #pragma unroll
        for (int e = 0; e < 16; ++e) {
            float v = p[e];
            if (v > v0)      { v1 = v0; i1 = i0; v0 = v; i0 = e; }
            else if (v > v1) { v1 = v;  i1 = e; }
        }
        route_e[t*2+0] = i0;  route_e[t*2+1] = i1;
        route_w[t*2+0] = __expf(v0 - m) / s;
        route_w[t*2+1] = __expf(v1 - m) / s;
    }
}

// ------- dispatch build: ballot rank/slot + inverse map smap + tile list -------
__global__ __launch_bounds__(1024)
void build_dispatch_k(const int* __restrict__ route_e, const float* __restrict__ route_w,
                      int* __restrict__ disp, int* __restrict__ smap, int* __restrict__ tmeta) {
    __shared__ unsigned char eidx[2 * T_TOK];
    __shared__ unsigned char keepf[2 * T_TOK];
    __shared__ int totals[NE];
    int tid = threadIdx.x;
    int wv = tid >> 6, lane = tid & 63;

    {   // route_e (8192 ints) -> bytes, coalesced
        int4 a = ((const int4*)route_e)[tid * 2];
        int4 b = ((const int4*)route_e)[tid * 2 + 1];
        unsigned int lo = (a.x & 0xff) | ((a.y & 0xff) << 8) | ((a.z & 0xff) << 16) | ((a.w & 0xff) << 24);
        unsigned int hi = (b.x & 0xff) | ((b.y & 0xff) << 8) | ((b.z & 0xff) << 16) | ((b.w & 0xff) << 24);
        uint2 pk; pk.x = lo; pk.y = hi;
        *(uint2*)(eidx + tid * 8) = pk;
    }
    for (int i = tid; i < 2 * T_TOK; i += 1024) smap[i] = -1;
    __syncthreads();

    unsigned long long below = (lane == 0) ? 0ull : ((~0ull) >> (64 - lane));
    #pragma unroll
    for (int s = 0; s < 2; ++s) {      // keep = token-order rank in (e,k) stream < CAP
        int st = wv + s * 16;
        int e = st >> 1, k = st & 1;
        int run = 0;
        for (int base = 0; base < T_TOK; base += 64) {
            int t = base + lane;
            int hit = (eidx[t * 2 + k] == e);
            unsigned long long m = __ballot(hit);
            int rank = run + __popcll(m & below);
            if (hit) keepf[t * 2 + k] = (rank < CAP) ? 1 : 0;
            run += __popcll(m);
        }
    }
    __syncthreads();

    {   // slot = flat-order rank among kept entries of expert e (one wave per expert)
        int e = wv;
        int run = 0;
        for (int base = 0; base < 2 * T_TOK; base += 64) {
            int f = base + lane;
            int hit = (eidx[f] == e) && keepf[f];
            unsigned long long m = __ballot(hit);
            int slot = run + __popcll(m & below);
            if (hit) {
                disp[e * CBUF + slot] = f >> 1;
                smap[f] = e * CBUF + slot;
            }
            run += __popcll(m);
        }
        if (lane == 0) totals[e] = run;
    }
    __syncthreads();

    for (int i = tid; i < NE * CBUF; i += 1024) {   // pad unused slots -> zero row
        int e = i / CBUF, s = i - e * CBUF;
        if (s >= totals[e]) disp[i] = T_TOK;
    }

    if (tid == 0) {   // active-tile list
        int n = 0;
        for (int e = 0; e < NE; ++e) {
            int ntl = (totals[e] + BM - 1) / BM;
            for (int m = 0; m < ntl; ++m) { tmeta[4 + n] = (e << 8) | m; ++n; }
        }
        tmeta[0] = n;
    }
}

// ---------------- GEMM1: xe @ {gate,up} fused + SiLU -> hidden (bf16) ----------------
// R8 pipeline (T4 counted-vmcnt): B-regs loaded 2 K-steps ahead; iter k packs
// B(k+1) (regs a full iteration old -> latency covered), issues A-DMA(k+1),
// loads B(k+2), computes MFMA(k), then drains ONLY the A-DMAs with vmcnt(4) --
// the 4 B(k+2) loads stay in flight across the barrier. sched_barrier(0) pins
// the A-before-B issue order that makes the literal count safe. No other VMEM
// in the loop (no spills: ~90 VGPR).
__global__ __launch_bounds__(256, 2)
void gemm1_k(const unsigned short* __restrict__ xb, const float* __restrict__ gw,
             const float* __restrict__ uw, const int* __restrict__ disp,
             const int* __restrict__ tmeta, unsigned short* __restrict__ hidden) {
    int slot = blockIdx.y;
    if (slot >= tmeta[0]) return;
    int pk = tmeta[4 + slot];
    int e = pk >> 8, mt = pk & 255;
    int m0 = mt * BM, n0 = blockIdx.x * BN;

    __shared__ unsigned short As[2 * BM * BK];   // 16 KB
    __shared__ unsigned short Bg[2 * BN * BK];   // 8 KB
    __shared__ unsigned short Bu[2 * BN * BK];   // 8 KB
    __shared__ int tok[BM];
    int tid = threadIdx.x;
    if (tid < BM) tok[tid] = disp[e * CBUF + m0 + tid];
    __syncthreads();

    int lane = tid & 63, w = tid >> 6;
    // ---- A staging (DMA) ----
    int cg = (lane & 3) ^ ((lane >> 3) & 3);   // swizzled source chunk
    int rl = lane >> 2;
    int rA0 = w * 32 + rl, rA1 = rA0 + 16;
    const unsigned short* srcA0 = xb + (size_t)tok[rA0] * DIM + cg * 8;
    const unsigned short* srcA1 = xb + (size_t)tok[rA1] * DIM + cg * 8;
    unsigned short* dA0 = As + (w * 32) * BK;
    unsigned short* dA1 = As + (w * 32 + 16) * BK;

    // ---- B staging (reg path): waves 0-1 gate, 2-3 up; 4k x 4n fp32 per thread ----
    int matb = tid >> 7;
    int kidx = (tid >> 4) & 7;
    int k4 = kidx * 4;
    int g = tid & 15;
    const float* Wsrc = (matb ? uw : gw) + (size_t)e * DIM * HID + (size_t)k4 * HID + n0 + g * 4;
    unsigned short* Bmine = matb ? Bu : Bg;
    int bOff = (((k4 >> 3) ^ (g & 3)) << 3) + ((k4 >> 2) & 1) * 4;   // u16 units

    int wm = w >> 1, wn = w & 1;
    int quad = lane >> 4, ln = lane & 15;
    int swqA = quad ^ ((ln >> 1) & 3);
    int swqB = quad ^ ((ln >> 2) & 3);

    f32x4 zero4 = {0.f, 0.f, 0.f, 0.f};
    f32x4 accg[4][2], accu[4][2];
    #pragma unroll
    for (int i = 0; i < 4; ++i)
        #pragma unroll
        for (int j = 0; j < 2; ++j) { accg[i][j] = zero4; accu[i][j] = zero4; }

    float4 p0, p1, p2, p3;   // B-regs pipeline (tile k+1 during iter k)

    // ---- prologue: B(0)+A(0) -> buf0; B(1) -> regs ----
    p0 = *(const float4*)(Wsrc);
    p1 = *(const float4*)(Wsrc + 1024);
    p2 = *(const float4*)(Wsrc + 2048);
    p3 = *(const float4*)(Wsrc + 3072);
    async16(srcA0, dA0); async16(srcA1, dA1);
    __builtin_amdgcn_sched_barrier(0);
    #pragma unroll
    for (int i = 0; i < 4; ++i) {           // pack B(0) (auto-waits the 4 loads)
        uint2 pkv;
        pkv.x = pack2bf(PICK4(p0, i), PICK4(p1, i));
        pkv.y = pack2bf(PICK4(p2, i), PICK4(p3, i));
        *(uint2*)(Bmine + (g * 4 + i) * BK + bOff) = pkv;
    }
    {
        const float* Ws = Wsrc + (size_t)BK * 1024;
        p0 = *(const float4*)(Ws);
        p1 = *(const float4*)(Ws + 1024);
        p2 = *(const float4*)(Ws + 2048);
        p3 = *(const float4*)(Ws + 3072);
    }
    // outstanding: [A-DMA x2 (older), B(1) x4]; retire A only
    asm volatile("s_waitcnt vmcnt(4) lgkmcnt(0)\n\ts_barrier" ::: "memory");

    for (int k0 = 0; k0 < DIM; k0 += BK) {
        int cur = (k0 >> 5) & 1, nx = cur ^ 1;
        const unsigned short* Ab = As + cur * (BM * BK);
        const unsigned short* Gb = Bg + cur * (BN * BK);
        const unsigned short* Ub = Bu + cur * (BN * BK);

        if (k0 + BK < DIM) {
            #pragma unroll
            for (int i = 0; i < 4; ++i) {   // pack B(k+1) -> nx (regs 1 iter old)
                uint2 pkv;
                pkv.x = pack2bf(PICK4(p0, i), PICK4(p1, i));
                pkv.y = pack2bf(PICK4(p2, i), PICK4(p3, i));
                *(uint2*)(Bmine + nx * (BN * BK) + (g * 4 + i) * BK + bOff) = pkv;
            }
            async16(srcA0 + k0 + BK, dA0 + nx * (BM * BK));
            async16(srcA1 + k0 + BK, dA1 + nx * (BM * BK));
            __builtin_amdgcn_sched_barrier(0);
            if (k0 + 2 * BK < DIM) {
                const float* Ws = Wsrc + (size_t)(k0 + 2 * BK) * 1024;
                p0 = *(const float4*)(Ws);
                p1 = *(const float4*)(Ws + 1024);
                p2 = *(const float4*)(Ws + 2048);
                p3 = *(const float4*)(Ws + 3072);
                __builtin_amdgcn_sched_barrier(0);
            }
        }

        short8 af[4], bgf[2], buf2[2];
        #pragma unroll
        for (int i = 0; i < 4; ++i)
            af[i] = *(const short8*)(Ab + (wm * 64 + i * 16 + ln) * BK + swqA * 8);
        #pragma unroll
        for (int j = 0; j < 2; ++j) {
            bgf[j]  = *(const short8*)(Gb + (wn * 32 + j * 16 + ln) * BK + swqB * 8);
            buf2[j] = *(const short8*)(Ub + (wn * 32 + j * 16 + ln) * BK + swqB * 8);
        }
        #pragma unroll
        for (int i = 0; i < 4; ++i)
            #pragma unroll
            for (int j = 0; j < 2; ++j) {
                accg[i][j] = __builtin_amdgcn_mfma_f32_16x16x32_bf16(af[i], bgf[j],  accg[i][j], 0, 0, 0);
                accu[i][j] = __builtin_amdgcn_mfma_f32_16x16x32_bf16(af[i], buf2[j], accu[i][j], 0, 0, 0);
            }

        if (k0 + BK < DIM) {
            if (k0 + 2 * BK < DIM)   // drain A-DMA(k+1) only; B(k+2) stays in flight
                asm volatile("s_waitcnt vmcnt(4) lgkmcnt(0)\n\ts_barrier" ::: "memory");
            else                     // no B-loads outstanding on last prefetch step
                asm volatile("s_waitcnt vmcnt(0) lgkmcnt(0)\n\ts_barrier" ::: "memory");
        }
    }
    #pragma unroll
    for (int i = 0; i < 4; ++i) {
        #pragma unroll
        for (int r = 0; r < 4; ++r) {
            int row = m0 + wm * 64 + i * 16 + quad * 4 + r;
            unsigned short* hrow = hidden + ((size_t)e * CBUF + row) * HID + n0 + wn * 32 + ln;
            #pragma unroll
            for (int j = 0; j < 2; ++j) {
                float gv = accg[i][j][r];
                float uv = accu[i][j][r];
                float sg = gv / (1.f + __expf(-gv));
                hrow[j * 16] = f2bf(sg * uv);
            }
        }
    }
}

// ---------------- GEMM2: hidden @ down -> ebuf (bf16, per expert slot) ----------------
// Same R8 counted-vmcnt pipeline; B from fp32 down_w [e][h][d] (h=k, d=n),
// 4k x 2n fp32 per thread.
__global__ __launch_bounds__(256, 2)
void gemm2_k(const unsigned short* __restrict__ hidden, const float* __restrict__ dw,
             const int* __restrict__ tmeta, unsigned short* __restrict__ ebuf) {
    int slot = blockIdx.y;
    if (slot >= tmeta[0]) return;
    int pk = tmeta[4 + slot];
    int e = pk >> 8, mt = pk & 255;
    int m0 = mt * BM, n0 = blockIdx.x * BN;

    __shared__ unsigned short As[2 * BM * BK];   // 16 KB
    __shared__ unsigned short Bs[2 * BN * BK];   // 8 KB
    int tid = threadIdx.x;

    int lane = tid & 63, w = tid >> 6;
    int cg = (lane & 3) ^ ((lane >> 3) & 3);
    int rl = lane >> 2;
    int rA0 = w * 32 + rl, rA1 = rA0 + 16;
    const unsigned short* srcA0 = hidden + ((size_t)e * CBUF + m0 + rA0) * HID + cg * 8;
    const unsigned short* srcA1 = hidden + ((size_t)e * CBUF + m0 + rA1) * HID + cg * 8;
    unsigned short* dA0 = As + (w * 32) * BK;
    unsigned short* dA1 = As + (w * 32 + 16) * BK;

    int g2 = tid & 31;
    int kidx2 = ((tid >> 5) & 3) | ((tid >> 7) << 2);
    int k4 = kidx2 * 4;
    const float* Wsrc = dw + (size_t)e * HID * DIM + (size_t)k4 * DIM + n0 + g2 * 2;
    int bOff = (((k4 >> 3) ^ ((g2 >> 1) & 3)) << 3) + ((k4 >> 2) & 1) * 4;

    int wm = w >> 1, wn = w & 1;
    int quad = lane >> 4, ln = lane & 15;
    int swqA = quad ^ ((ln >> 1) & 3);
    int swqB = quad ^ ((ln >> 2) & 3);

    f32x4 zero4 = {0.f, 0.f, 0.f, 0.f};
    f32x4 acc[4][2];
    #pragma unroll
    for (int i = 0; i < 4; ++i)
        #pragma unroll
        for (int j = 0; j < 2; ++j) acc[i][j] = zero4;

    float2 p0, p1, p2, p3;

    // ---- prologue ----
    p0 = *(const float2*)(Wsrc);
    p1 = *(const float2*)(Wsrc + 1024);
    p2 = *(const float2*)(Wsrc + 2048);
    p3 = *(const float2*)(Wsrc + 3072);
    async16(srcA0, dA0); async16(srcA1, dA1);
    __builtin_amdgcn_sched_barrier(0);
    #pragma unroll
    for (int i = 0; i < 2; ++i) {
        uint2 pkv;
        pkv.x = pack2bf(i ? p0.y : p0.x, i ? p1.y : p1.x);
        pkv.y = pack2bf(i ? p2.y : p2.x, i ? p3.y : p3.x);
        *(uint2*)(Bs + (g2 * 2 + i) * BK + bOff) = pkv;
    }
    {
        const float* Ws = Wsrc + (size_t)BK * 1024;
        p0 = *(const float2*)(Ws);
        p1 = *(const float2*)(Ws + 1024);
        p2 = *(const float2*)(Ws + 2048);
        p3 = *(const float2*)(Ws + 3072);
    }
    asm volatile("s_waitcnt vmcnt(4) lgkmcnt(0)\n\ts_barrier" ::: "memory");

    for (int k0 = 0; k0 < HID; k0 += BK) {
        int cur = (k0 >> 5) & 1, nx = cur ^ 1;
        const unsigned short* Ab = As + cur * (BM * BK);
        const unsigned short* Bb = Bs + cur * (BN * BK);

        if (k0 + BK < HID) {
            #pragma unroll
            for (int i = 0; i < 2; ++i) {
                uint2 pkv;
                pkv.x = pack2bf(i ? p0.y : p0.x, i ? p1.y : p1.x);
                pkv.y = pack2bf(i ? p2.y : p2.x, i ? p3.y : p3.x);
                *(uint2*)(Bs + nx * (BN * BK) + (g2 * 2 + i) * BK + bOff) = pkv;
            }
            async16(srcA0 + k0 + BK, dA0 + nx * (BM * BK));
            async16(srcA1 + k0 + BK, dA1 + nx * (BM * BK));
            __builtin_amdgcn_sched_barrier(0);
            if (k0 + 2 * BK < HID) {
                const float* Ws = Wsrc + (size_t)(k0 + 2 * BK) * 1024;
                p0 = *(const float2*)(Ws);
                p1 = *(const float2*)(Ws + 1024);
                p2 = *(const float2*)(Ws + 2048);
                p3 = *(const float2*)(Ws + 3072);
                __builtin_amdgcn_sched_barrier(0);
            }
        }

        short8 af[4], bf[2];
        #pragma unroll
        for (int i = 0; i < 4; ++i)
            af[i] = *(const short8*)(Ab + (wm * 64 + i * 16 + ln) * BK + swqA * 8);
        #pragma unroll
        for (int j = 0; j < 2; ++j)
            bf[j] = *(const short8*)(Bb + (wn * 32 + j * 16 + ln) * BK + swqB * 8);
        #pragma unroll
        for (int i = 0; i < 4; ++i)
            #pragma unroll
            for (int j = 0; j < 2; ++j)
                acc[i][j] = __builtin_amdgcn_mfma_f32_16x16x32_bf16(af[i], bf[j], acc[i][j], 0, 0, 0);

        if (k0 + BK < HID) {
            if (k0 + 2 * BK < HID)
                asm volatile("s_waitcnt vmcnt(4) lgkmcnt(0)\n\ts_barrier" ::: "memory");
            else
                asm volatile("s_waitcnt vmcnt(0) lgkmcnt(0)\n\ts_barrier" ::: "memory");
        }
    }
    #pragma unroll
    for (int i = 0; i < 4; ++i) {
        #pragma unroll
        for (int r = 0; r < 4; ++r) {
            int row = m0 + wm * 64 + i * 16 + quad * 4 + r;
            unsigned short* erow = ebuf + ((size_t)e * CBUF + row) * DIM + n0 + wn * 32 + ln;
            #pragma unroll
            for (int j = 0; j < 2; ++j)
                erow[j * 16] = f2bf(acc[i][j][r]);
        }
    }
}

// ---------------- combine: out[t] = sum_k w[t,k] * ebuf[smap[t,k]] ----------------
__global__ __launch_bounds__(256)
void combine_k(const unsigned short* __restrict__ ebuf, const int* __restrict__ smap,
               const float* __restrict__ rwt, float* __restrict__ out) {
    int t = blockIdx.x * 2 + (threadIdx.x >> 7);
    int c = (threadIdx.x & 127) * 8;
    float acc[8];
    #pragma unroll
    for (int j = 0; j < 8; ++j) acc[j] = 0.f;
    #pragma unroll
    for (int k = 0; k < 2; ++k) {
        int sm = smap[t * 2 + k];
        if (sm >= 0) {
            float wgt = rwt[t * 2 + k];
            uint4 rv = *(const uint4*)(ebuf + (size_t)sm * DIM + c);
            unsigned int d[4] = {rv.x, rv.y, rv.z, rv.w};
            #pragma unroll
            for (int q = 0; q < 4; ++q) {
                acc[q * 2 + 0] += wgt * __uint_as_float(d[q] << 16);
                acc[q * 2 + 1] += wgt * __uint_as_float(d[q] & 0xffff0000u);
            }
        }
    }
    float4 o0 = {acc[0], acc[1], acc[2], acc[3]};
    float4 o1 = {acc[4], acc[5], acc[6], acc[7]};
    float* orow = out + (size_t)t * DIM + c;
    *(float4*)(orow + 0) = o0;
    *(float4*)(orow + 4) = o1;
}

extern "C" void kernel_launch(void* const* d_in, const int* in_sizes, int n_in,
                              void* d_out, int out_size, void* d_ws, size_t ws_size,
                              hipStream_t stream) {
    const float* x  = (const float*)d_in[0];   // (2,2048,1024)
    const float* rw = (const float*)d_in[1];   // (1024,16)
    const float* gw = (const float*)d_in[2];   // (16,1024,1024) [e][d][h]
    const float* uw = (const float*)d_in[3];   // (16,1024,1024) [e][d][h]
    const float* dw = (const float*)d_in[4];   // (16,1024,1024) [e][h][d]
    float* out = (float*)d_out;

    char* ws = (char*)d_ws;
    size_t off = 0;
    auto alloc = [&](size_t bytes) { void* p = ws + off; off += (bytes + 255) & ~(size_t)255; return p; };
    unsigned short* xb   = (unsigned short*)alloc((size_t)(T_TOK + 1) * DIM * 2);
    unsigned short* hid  = (unsigned short*)alloc((size_t)NE * CBUF * HID * 2);
    unsigned short* ebuf = (unsigned short*)alloc((size_t)NE * CBUF * DIM * 2);
    int*   disp   = (int*)alloc((size_t)NE * CBUF * 4);
    int*   smap   = (int*)alloc((size_t)T_TOK * 2 * 4);
    int*   tmeta  = (int*)alloc((4 + MAXTILE) * 4);
    int*   re     = (int*)alloc((size_t)T_TOK * 2 * 4);
    float* rwt    = (float*)alloc((size_t)T_TOK * 2 * 4);
    (void)ws_size; (void)in_sizes; (void)n_in;

    convert_x_k<<<T_TOK + 1, 256, 0, stream>>>(x, xb);
    router_k<<<T_TOK, 64, 0, stream>>>(x, rw, re, rwt);
    build_dispatch_k<<<1, 1024, 0, stream>>>(re, rwt, disp, smap, tmeta);
    gemm1_k<<<dim3(HID / BN, MAXTILE), 256, 0, stream>>>(xb, gw, uw, disp, tmeta, hid);
    gemm2_k<<<dim3(DIM / BN, MAXTILE), 256, 0, stream>>>(hid, dw, tmeta, ebuf);
    combine_k<<<T_TOK / 2, 256, 0, stream>>>(ebuf, smap, rwt, out);
}